// Round 1
// baseline (736.806 us; speedup 1.0000x reference)
//
#include <hip/hip_runtime.h>
#include <math.h>

#define NB 4
#define CIN 64
#define COUT 64
#define H 128
#define W 128
#define H2 256
#define W2 256
#define KB 9
#define RAD 4
#define TY 16
#define TX 16
#define HALO 24       // TY + 2*RAD
#define HSTR 25       // halo row stride (+1 pad)
#define PAD_PAIRS 20  // max nonzero (tap) entries per basis k is 19
#define NPX 256       // TY*TX

// ws layout (float units)
#define WS_PAIRS 0                    // int2[9*PAD_PAIRS] = 360 floats
#define WS_P1    1024                 // per-tile partial sums  [4*64][256]
#define WS_P2    (1024 + 65536)       // per-tile partial sumsq [4*64][256]
#define WS_MU    (1024 + 131072)      // mu[256]
#define WS_RSTD  (WS_MU + 256)        // rstd[256]

// ---------------------------------------------------------------------------
// Setup: compute DISCO basis psi (double, matching numpy) and build a compact
// per-k tap list (halo offset, value), padded to PAD_PAIRS with zeros.
// ---------------------------------------------------------------------------
__global__ void setup_kernel(float* __restrict__ ws) {
    __shared__ float psi[81 * 9];
    const int tid = threadIdx.x;
    const double hy   = 1.0 / 256.0;
    const double rcut = 0.015;        // RADIUS_CUTOFF / 2
    const double dr   = 0.0075;       // rcut / (nr-1)
    const double PI_  = 3.14159265358979323846;
    const double dphi = PI_ / 2.0;
    const double TWO_PI = 2.0 * PI_;

    for (int e = tid; e < 81 * 9; e += blockDim.x) {
        int t = e / 9, k = e - t * 9;
        int ky = t / 9, kx = t - ky * 9;
        double dyv = (double)(ky - 4) * hy;
        double dxv = (double)(kx - 4) * hy;
        double r = sqrt(dyv * dyv + dxv * dxv);
        int ir = (k == 0) ? 0 : ((k - 1) / 4 + 1);
        double rv = 0.0;
        if (fabs(r - ir * dr) <= dr && r <= rcut) rv = 1.0 - fabs(r - ir * dr) / dr;
        double val;
        if (k == 0) {
            val = rv;
        } else {
            double phi = atan2(dyv, dxv);
            phi = fmod(phi, TWO_PI);
            if (phi < 0.0) phi += TWO_PI;
            int ip = (k - 1) & 3;
            double da = fabs(phi - (double)ip * dphi);
            da = fmin(da, TWO_PI - da);
            double pv = (da <= dphi) ? 1.0 - da / dphi : 0.0;
            val = rv * pv;
        }
        val *= hy * hy;               // quadrature weight hx*hy
        psi[e] = (float)val;
    }
    __syncthreads();
    if (tid < 9) {
        int2* pairs = (int2*)ws;
        int cnt = 0;
        for (int t = 0; t < 81 && cnt < PAD_PAIRS; ++t) {
            float v = psi[t * 9 + tid];
            if (v != 0.f) {
                int off = (t / 9) * HSTR + (t % 9);   // halo offset of tap
                pairs[tid * PAD_PAIRS + cnt] = make_int2(off, __float_as_int(v));
                ++cnt;
            }
        }
        for (; cnt < PAD_PAIRS; ++cnt) pairs[tid * PAD_PAIRS + cnt] = make_int2(0, 0);
    }
}

// ---------------------------------------------------------------------------
// Fused upsample + DISCO conv. One block = one 16x16 output tile of one image.
// Per input channel: stage bilinear-upsampled halo (24x24) to LDS, compute
// z[k=0..8] per pixel via sparse taps, then rank-9 outer-product GEMM into
// 8x8 per-thread fp32 accumulators (64 outs x 256 px per block).
// ---------------------------------------------------------------------------
__global__ __launch_bounds__(256) void conv_kernel(const float* __restrict__ img,
                                                   const float* __restrict__ wgt,
                                                   float* __restrict__ out,
                                                   float* __restrict__ ws) {
    __shared__ float halo[HALO * HSTR];
    __shared__ __align__(16) float zbuf[9 * NPX];
    __shared__ __align__(16) float wT[9 * 64];
    __shared__ int2 spairs[9 * PAD_PAIRS];

    const int tid  = threadIdx.x;
    const int bid  = blockIdx.x;
    const int n    = bid >> 8;
    const int tile = bid & 255;
    const int ty0  = (tile >> 4) << 4;
    const int tx0  = (tile & 15) << 4;

    if (tid < 9 * PAD_PAIRS) spairs[tid] = ((const int2*)ws)[tid];

    float acc[8][8];
#pragma unroll
    for (int a = 0; a < 8; ++a)
#pragma unroll
        for (int b = 0; b < 8; ++b) acc[a][b] = 0.f;

    const float cs = (float)(127.0 / 255.0);       // align_corners scale, f32
    const int hbase = (tid >> 4) * HSTR + (tid & 15);
    const int og = tid >> 5;        // 8 groups of 8 output channels
    const int pg = tid & 31;        // 32 groups of 8 pixels

    for (int i = 0; i < CIN; ++i) {
        __syncthreads();   // prev iter's reads of halo/wT/zbuf complete
        // stage weight slice, transposed to wT[k][o]
        for (int e = tid; e < 576; e += 256) {
            int o = e / 9, k = e - o * 9;
            wT[k * 64 + o] = wgt[(o * CIN + i) * KB + k];
        }
        // stage upsampled halo for this channel
        const float* imc = img + (size_t)(n * CIN + i) * H * W;
        for (int e = tid; e < HALO * HALO; e += 256) {
            int hy_i = e / HALO, hx_i = e - hy_i * HALO;
            int uy = ty0 - RAD + hy_i;
            int ux = tx0 - RAD + hx_i;
            float v = 0.f;
            if ((unsigned)uy < (unsigned)H2 && (unsigned)ux < (unsigned)W2) {
                float sy = (float)uy * cs; int y0 = (int)sy; float fy = sy - (float)y0;
                int y1 = min(y0 + 1, H - 1);
                float sx = (float)ux * cs; int x0 = (int)sx; float fx = sx - (float)x0;
                int x1 = min(x0 + 1, W - 1);
                float a00 = imc[y0 * W + x0], a01 = imc[y0 * W + x1];
                float a10 = imc[y1 * W + x0], a11 = imc[y1 * W + x1];
                float t0 = a00 * (1.f - fy) + a10 * fy;   // y-axis first (matches ref)
                float t1 = a01 * (1.f - fy) + a11 * fy;
                v = t0 * (1.f - fx) + t1 * fx;
            }
            halo[hy_i * HSTR + hx_i] = v;
        }
        __syncthreads();
        // z[k] per pixel via sparse taps (compile-time bounds, static indexing)
#pragma unroll
        for (int k = 0; k < 9; ++k) {
            float zk = 0.f;
#pragma unroll
            for (int j = 0; j < PAD_PAIRS; ++j) {
                int2 pr = spairs[k * PAD_PAIRS + j];
                zk = fmaf(__int_as_float(pr.y), halo[hbase + pr.x], zk);
            }
            zbuf[k * NPX + tid] = zk;
        }
        __syncthreads();
        // rank-9 GEMM accumulate: acc[a][b] += wT[k][og*8+a] * z[k][pg*8+b]
#pragma unroll
        for (int k = 0; k < 9; ++k) {
            const float4 z0 = *(const float4*)&zbuf[k * NPX + pg * 8];
            const float4 z1 = *(const float4*)&zbuf[k * NPX + pg * 8 + 4];
            const float4 w0 = *(const float4*)&wT[k * 64 + og * 8];
            const float4 w1 = *(const float4*)&wT[k * 64 + og * 8 + 4];
            float zz[8] = {z0.x, z0.y, z0.z, z0.w, z1.x, z1.y, z1.z, z1.w};
            float wv[8] = {w0.x, w0.y, w0.z, w0.w, w1.x, w1.y, w1.z, w1.w};
#pragma unroll
            for (int a = 0; a < 8; ++a)
#pragma unroll
                for (int b = 0; b < 8; ++b)
                    acc[a][b] = fmaf(wv[a], zz[b], acc[a][b]);
        }
    }

    // epilogue: store y + per-tile partial sums for instance norm
    const int p0  = pg * 8;
    const int Y   = ty0 + (p0 >> 4);
    const int X   = tx0 + (p0 & 15);
    float psum[8], psq[8];
#pragma unroll
    for (int a = 0; a < 8; ++a) {
        int o = og * 8 + a;
        float* op = out + (((size_t)(n * COUT + o) * H2 + Y) * W2 + X);
        *(float4*)op        = make_float4(acc[a][0], acc[a][1], acc[a][2], acc[a][3]);
        *(float4*)(op + 4)  = make_float4(acc[a][4], acc[a][5], acc[a][6], acc[a][7]);
        float s = 0.f, q = 0.f;
#pragma unroll
        for (int b = 0; b < 8; ++b) { s += acc[a][b]; q = fmaf(acc[a][b], acc[a][b], q); }
        psum[a] = s; psq[a] = q;
    }
#pragma unroll
    for (int a = 0; a < 8; ++a) {
#pragma unroll
        for (int m = 1; m < 32; m <<= 1) {
            psum[a] += __shfl_xor(psum[a], m);
            psq[a]  += __shfl_xor(psq[a], m);
        }
    }
    if (pg == 0) {
#pragma unroll
        for (int a = 0; a < 8; ++a) {
            int o = og * 8 + a;
            ws[WS_P1 + (n * COUT + o) * 256 + tile] = psum[a];
            ws[WS_P2 + (n * COUT + o) * 256 + tile] = psq[a];
        }
    }
}

// ---------------------------------------------------------------------------
// Stats: reduce 256 tile-partials per (n,c); mu and rstd (biased var + eps)
// ---------------------------------------------------------------------------
__global__ void stats_kernel(float* __restrict__ ws) {
    const int co  = blockIdx.x;     // 0..255
    const int tid = threadIdx.x;    // 256
    float s1 = ws[WS_P1 + co * 256 + tid];
    float s2 = ws[WS_P2 + co * 256 + tid];
#pragma unroll
    for (int m = 1; m < 64; m <<= 1) { s1 += __shfl_xor(s1, m); s2 += __shfl_xor(s2, m); }
    __shared__ float r1[4], r2[4];
    if ((tid & 63) == 0) { r1[tid >> 6] = s1; r2[tid >> 6] = s2; }
    __syncthreads();
    if (tid == 0) {
        float S1 = r1[0] + r1[1] + r1[2] + r1[3];
        float S2 = r2[0] + r2[1] + r2[2] + r2[3];
        const float inv = 1.f / 65536.f;
        float mu  = S1 * inv;
        float var = S2 * inv - mu * mu;
        ws[WS_MU + co]   = mu;
        ws[WS_RSTD + co] = 1.f / sqrtf(var + 1e-5f);
    }
}

// ---------------------------------------------------------------------------
// Normalize + LeakyReLU(0.2), in place on d_out (float4 vectorized)
// ---------------------------------------------------------------------------
__global__ void norm_kernel(float* __restrict__ out, const float* __restrict__ ws) {
    const int total = NB * COUT * H2 * W2 / 4;   // float4 count
    for (int idx = blockIdx.x * blockDim.x + threadIdx.x; idx < total;
         idx += gridDim.x * blockDim.x) {
        int co = idx >> 14;                      // 16384 float4 per (n,c)
        float mu = ws[WS_MU + co];
        float rs = ws[WS_RSTD + co];
        float4 v = ((float4*)out)[idx];
        float* p = (float*)&v;
#pragma unroll
        for (int j = 0; j < 4; ++j) {
            float t = (p[j] - mu) * rs;
            p[j] = (t >= 0.f) ? t : 0.2f * t;
        }
        ((float4*)out)[idx] = v;
    }
}

extern "C" void kernel_launch(void* const* d_in, const int* in_sizes, int n_in,
                              void* d_out, int out_size, void* d_ws, size_t ws_size,
                              hipStream_t stream) {
    const float* img = (const float*)d_in[0];
    const float* wgt = (const float*)d_in[1];
    float* out = (float*)d_out;
    float* ws  = (float*)d_ws;

    setup_kernel<<<1, 256, 0, stream>>>(ws);
    conv_kernel<<<NB * 256, 256, 0, stream>>>(img, wgt, out, ws);
    stats_kernel<<<256, 256, 0, stream>>>(ws);
    norm_kernel<<<2048, 256, 0, stream>>>(out, ws);
}

// Round 2
// 373.669 us; speedup vs baseline: 1.9718x; 1.9718x over previous
//
#include <hip/hip_runtime.h>

#define NB 4
#define CIN 64
#define COUT 64
#define H 128
#define W 128
#define H2 256
#define W2 256
#define HALO 22       // 16 + 2*3 (true psi support is +/-3 px)
#define HSTR 23

// ws layout (float units)
#define WS_P1    0                    // per-tile partial sums  [4*64][256]
#define WS_P2    65536                // per-tile partial sumsq [4*64][256]
#define WS_MU    131072
#define WS_RSTD  131328

// ---------------------------------------------------------------------------
// Compile-time DISCO basis (replicates the numpy double-precision computation)
// ---------------------------------------------------------------------------
constexpr double csqrt(double x) {
    double g = x > 1.0 ? x : 1.0;
    for (int i = 0; i < 64; ++i) g = 0.5 * (g + x / g);
    return g;
}
constexpr double catan_pos(double x) {   // atan for x >= 0
    double f = 1.0;
    for (int i = 0; i < 6; ++i) { x = x / (1.0 + csqrt(1.0 + x * x)); f *= 2.0; }
    double x2 = x * x, s = 0.0, term = x;
    for (int n = 0; n < 10; ++n) { s += term / (2 * n + 1) * ((n & 1) ? -1.0 : 1.0); term *= x2; }
    return f * s;
}
constexpr double catan2(double y, double x) {
    const double PI = 3.141592653589793;
    if (x == 0.0 && y == 0.0) return 0.0;
    double ax = x < 0 ? -x : x, ay = y < 0 ? -y : y;
    double a = (ax >= ay) ? catan_pos(ay / ax) : (PI / 2.0 - catan_pos(ax / ay));
    if (x < 0) a = PI - a;
    return (y < 0) ? -a : a;
}

struct PsiTab { double v[81][9]; };
constexpr PsiTab compute_psi() {
    PsiTab P{};
    const double hy = 1.0 / 256.0;
    const double rcut = 0.03 / 2.0;
    const double dr = rcut / 2.0;
    const double PI = 3.141592653589793;
    const double TWO_PI = 6.283185307179586;
    const double dphi = PI / 2.0;
    for (int ky = 0; ky < 9; ++ky)
        for (int kx = 0; kx < 9; ++kx) {
            double dy = (double)(ky - 4) * hy;
            double dx = (double)(kx - 4) * hy;
            double r = csqrt(dy * dy + dx * dx);
            double phi = catan2(dy, dx);
            if (phi < 0.0) phi += TWO_PI;
            for (int k = 0; k < 9; ++k) {
                int ir = (k == 0) ? 0 : ((k - 1) / 4 + 1);
                double ctr = ir * dr;
                double ad = r > ctr ? r - ctr : ctr - r;
                double rv = (ad <= dr && r <= rcut) ? 1.0 - ad / dr : 0.0;
                double val;
                if (k == 0) val = rv;
                else {
                    int ip = (k - 1) % 4;
                    double da = phi - ip * dphi; if (da < 0) da = -da;
                    double d2 = TWO_PI - da; if (d2 < da) da = d2;
                    double pv = (da <= dphi) ? 1.0 - da / dphi : 0.0;
                    val = rv * pv;
                }
                P.v[ky * 9 + kx][k] = val * (hy * hy);
            }
        }
    return P;
}

struct TapTab {
    int nt;
    int off[48];          // (dy+3)*HSTR + (dx+3), dword offset from thread base
    float val[48][9];
    bool nz[48][9];
};
constexpr TapTab make_taps() {
    TapTab T{};
    PsiTab P = compute_psi();
    for (int ky = 0; ky < 9; ++ky)
        for (int kx = 0; kx < 9; ++kx) {
            int t = ky * 9 + kx;
            bool any = false;
            for (int k = 0; k < 9; ++k) if (P.v[t][k] != 0.0) any = true;
            if (!any) continue;
            int dy = ky - 4, dx = kx - 4;   // guaranteed within [-3,3] (support r<=3.84px)
            T.off[T.nt] = (dy + 3) * HSTR + (dx + 3);
            for (int k = 0; k < 9; ++k) {
                T.val[T.nt][k] = (float)P.v[t][k];
                T.nz[T.nt][k] = (P.v[t][k] != 0.0);
            }
            T.nt++;
        }
    return T;
}
constexpr TapTab TT = make_taps();
constexpr int NT = TT.nt;
static_assert(NT > 0 && NT <= 48, "tap table overflow");

using f32x4  = __attribute__((ext_vector_type(4))) float;
using bf16x8 = __attribute__((ext_vector_type(8))) short;

__device__ __forceinline__ unsigned short f2bf(float f) {
    unsigned u = __float_as_uint(f);
    unsigned r = (u + 0x7fff + ((u >> 16) & 1)) >> 16;   // RNE
    return (unsigned short)r;
}

// ---------------------------------------------------------------------------
// Fused upsample + DISCO conv. Block = 16x16 px tile, 4 waves.
// Per channel-pair: stage bilinear halo -> z[k] per px (compile-time taps) ->
// bf16 zbuf -> MFMA 16x16x32 (K=32 = 2ch x 16 with zero-padded rows 9..15).
// ---------------------------------------------------------------------------
__global__ __launch_bounds__(256) void conv_kernel(const float* __restrict__ img,
                                                   const float* __restrict__ wgt,
                                                   float* __restrict__ out,
                                                   float* __restrict__ ws) {
    __shared__ unsigned short zbuf[256][40];   // [px][k] bf16, rows 9..15/25..31 zero
    __shared__ unsigned short wbuf[64][40];    // [o][k]  bf16
    __shared__ float halo[2][HALO * HSTR];
    __shared__ float red1[4][64], red2[4][64];

    const int tid  = threadIdx.x;
    const int bid  = blockIdx.x;
    const int n    = bid >> 8;
    const int tile = bid & 255;
    const int ty0  = (tile >> 4) << 4;
    const int tx0  = (tile & 15) << 4;

    const int r = tid >> 4, c = tid & 15;
    const int hbase = r * HSTR + c;
    const int wv  = tid >> 6;          // wave id
    const int l   = tid & 63;          // lane
    const int a16 = l & 15;
    const int kseg = (l >> 4) * 8;

    // one-time zero of zbuf/wbuf (pads stay zero forever -> safe 0*0 MFMA pad)
    {
        uint4* zr = (uint4*)&zbuf[tid][0];
#pragma unroll
        for (int j = 0; j < 5; ++j) zr[j] = make_uint4(0, 0, 0, 0);
        if (tid < 64) {
            uint4* wr = (uint4*)&wbuf[tid][0];
#pragma unroll
            for (int j = 0; j < 5; ++j) wr[j] = make_uint4(0, 0, 0, 0);
        }
    }

    f32x4 acc[4][4];
#pragma unroll
    for (int m = 0; m < 4; ++m)
#pragma unroll
        for (int t = 0; t < 4; ++t) acc[m][t] = (f32x4){0.f, 0.f, 0.f, 0.f};

    const float cs = (float)(127.0 / 255.0);

    auto stage_halo = [&](float* hb, int ich) {
        const float* imc = img + ((size_t)n * CIN + ich) * (H * W);
        for (int e = tid; e < HALO * HALO; e += 256) {
            int hy_i = e / HALO, hx_i = e - hy_i * HALO;
            int uy = ty0 - 3 + hy_i;
            int ux = tx0 - 3 + hx_i;
            float v = 0.f;
            if ((unsigned)uy < (unsigned)H2 && (unsigned)ux < (unsigned)W2) {
                float sy = (float)uy * cs; int y0 = (int)sy; float fy = sy - (float)y0;
                int y1 = min(y0 + 1, H - 1);
                float sx = (float)ux * cs; int x0 = (int)sx; float fx = sx - (float)x0;
                int x1 = min(x0 + 1, W - 1);
                float a00 = imc[y0 * W + x0], a01 = imc[y0 * W + x1];
                float a10 = imc[y1 * W + x0], a11 = imc[y1 * W + x1];
                float t0 = a00 * (1.f - fy) + a10 * fy;
                float t1 = a01 * (1.f - fy) + a11 * fy;
                v = t0 * (1.f - fx) + t1 * fx;
            }
            hb[hy_i * HSTR + hx_i] = v;
        }
    };

    auto zphase = [&](const float* hb, int co) {
        float zk[9] = {0.f, 0.f, 0.f, 0.f, 0.f, 0.f, 0.f, 0.f, 0.f};
#pragma unroll
        for (int t = 0; t < NT; ++t) {
            float h = hb[hbase + TT.off[t]];
#pragma unroll
            for (int k = 0; k < 9; ++k)
                if (TT.nz[t][k]) zk[k] = fmaf(TT.val[t][k], h, zk[k]);
        }
        unsigned short* zr = &zbuf[tid][co];
        *(unsigned*)&zr[0] = (unsigned)f2bf(zk[0]) | ((unsigned)f2bf(zk[1]) << 16);
        *(unsigned*)&zr[2] = (unsigned)f2bf(zk[2]) | ((unsigned)f2bf(zk[3]) << 16);
        *(unsigned*)&zr[4] = (unsigned)f2bf(zk[4]) | ((unsigned)f2bf(zk[5]) << 16);
        *(unsigned*)&zr[6] = (unsigned)f2bf(zk[6]) | ((unsigned)f2bf(zk[7]) << 16);
        zr[8] = f2bf(zk[8]);
    };

#pragma unroll 1
    for (int g = 0; g < 32; ++g) {
        __syncthreads();                       // prev MFMA reads done
        // stage weights for both channels of the pair (bf16)
        for (int e = tid; e < 1152; e += 256) {
            int ch = (e >= 576) ? 1 : 0;
            int eo = e - ch * 576;
            int o = eo / 9, k = eo - o * 9;
            float wval = wgt[((size_t)o * CIN + (2 * g + ch)) * 9 + k];
            wbuf[o][ch * 16 + k] = f2bf(wval);
        }
        stage_halo(halo[0], 2 * g);
        __syncthreads();
        zphase(halo[0], 0);
        stage_halo(halo[1], 2 * g + 1);
        __syncthreads();
        zphase(halo[1], 16);
        __syncthreads();
        // MFMA: wave wv owns o 0..63 x px [wv*64, wv*64+64)
        bf16x8 af[4], bf[4];
#pragma unroll
        for (int m = 0; m < 4; ++m)
            af[m] = *(const bf16x8*)&wbuf[m * 16 + a16][kseg];
#pragma unroll
        for (int t = 0; t < 4; ++t)
            bf[t] = *(const bf16x8*)&zbuf[wv * 64 + t * 16 + a16][kseg];
#pragma unroll
        for (int m = 0; m < 4; ++m)
#pragma unroll
            for (int t = 0; t < 4; ++t)
                acc[m][t] = __builtin_amdgcn_mfma_f32_16x16x32_bf16(af[m], bf[t], acc[m][t], 0, 0, 0);
    }

    // epilogue: per-o partial sums (instance norm) + store y
#pragma unroll
    for (int m = 0; m < 4; ++m) {
#pragma unroll
        for (int r4 = 0; r4 < 4; ++r4) {
            float s = 0.f, q = 0.f;
#pragma unroll
            for (int t = 0; t < 4; ++t) {
                float v = acc[m][t][r4];
                s += v; q = fmaf(v, v, q);
            }
#pragma unroll
            for (int msk = 1; msk < 16; msk <<= 1) {
                s += __shfl_xor(s, msk);
                q += __shfl_xor(q, msk);
            }
            if ((l & 15) == 0) {
                int o = m * 16 + (l >> 4) * 4 + r4;
                red1[wv][o] = s;
                red2[wv][o] = q;
            }
        }
    }

    const size_t outbase = (size_t)n * COUT * (size_t)(H2 * W2);
#pragma unroll
    for (int m = 0; m < 4; ++m)
#pragma unroll
        for (int t = 0; t < 4; ++t) {
            int Y = ty0 + wv * 4 + t;
            int X = tx0 + a16;
#pragma unroll
            for (int r4 = 0; r4 < 4; ++r4) {
                int o = m * 16 + (l >> 4) * 4 + r4;
                out[outbase + (size_t)o * (H2 * W2) + Y * W2 + X] = acc[m][t][r4];
            }
        }
    __syncthreads();
    if (tid < 64) {
        float S1 = red1[0][tid] + red1[1][tid] + red1[2][tid] + red1[3][tid];
        float S2 = red2[0][tid] + red2[1][tid] + red2[2][tid] + red2[3][tid];
        ws[WS_P1 + (n * COUT + tid) * 256 + tile] = S1;
        ws[WS_P2 + (n * COUT + tid) * 256 + tile] = S2;
    }
}

// ---------------------------------------------------------------------------
// Stats: reduce 256 tile-partials per (n,c)
// ---------------------------------------------------------------------------
__global__ void stats_kernel(float* __restrict__ ws) {
    const int co  = blockIdx.x;
    const int tid = threadIdx.x;
    float s1 = ws[WS_P1 + co * 256 + tid];
    float s2 = ws[WS_P2 + co * 256 + tid];
#pragma unroll
    for (int m = 1; m < 64; m <<= 1) { s1 += __shfl_xor(s1, m); s2 += __shfl_xor(s2, m); }
    __shared__ float r1[4], r2[4];
    if ((tid & 63) == 0) { r1[tid >> 6] = s1; r2[tid >> 6] = s2; }
    __syncthreads();
    if (tid == 0) {
        float S1 = r1[0] + r1[1] + r1[2] + r1[3];
        float S2 = r2[0] + r2[1] + r2[2] + r2[3];
        const float inv = 1.f / 65536.f;
        float mu  = S1 * inv;
        float var = S2 * inv - mu * mu;
        ws[WS_MU + co]   = mu;
        ws[WS_RSTD + co] = 1.f / sqrtf(var + 1e-5f);
    }
}

// ---------------------------------------------------------------------------
// Normalize + LeakyReLU(0.2), in place on d_out
// ---------------------------------------------------------------------------
__global__ void norm_kernel(float* __restrict__ out, const float* __restrict__ ws) {
    const int total = NB * COUT * H2 * W2 / 4;
    for (int idx = blockIdx.x * blockDim.x + threadIdx.x; idx < total;
         idx += gridDim.x * blockDim.x) {
        int co = idx >> 14;
        float mu = ws[WS_MU + co];
        float rs = ws[WS_RSTD + co];
        float4 v = ((float4*)out)[idx];
        float* p = (float*)&v;
#pragma unroll
        for (int j = 0; j < 4; ++j) {
            float t = (p[j] - mu) * rs;
            p[j] = (t >= 0.f) ? t : 0.2f * t;
        }
        ((float4*)out)[idx] = v;
    }
}

extern "C" void kernel_launch(void* const* d_in, const int* in_sizes, int n_in,
                              void* d_out, int out_size, void* d_ws, size_t ws_size,
                              hipStream_t stream) {
    const float* img = (const float*)d_in[0];
    const float* wgt = (const float*)d_in[1];
    float* out = (float*)d_out;
    float* ws  = (float*)d_ws;

    conv_kernel<<<NB * 256, 256, 0, stream>>>(img, wgt, out, ws);
    stats_kernel<<<256, 256, 0, stream>>>(ws);
    norm_kernel<<<2048, 256, 0, stream>>>(out, ws);
}